// Round 3
// baseline (3580.210 us; speedup 1.0000x reference)
//
#include <hip/hip_runtime.h>
#include <math.h>

#define N_NODES 50000
#define N_EDGES 600000
#define IN_DIM 64
#define DMODEL 128
#define N_LAYERS 8
#define N_ETYPES 44
#define N_MENTIONS 100000
#define N_VARS 20000
#define OUT_DIM 100

// ---------------- GEMM (fp32, 64x64 tile, BK=16, 256 thr, 4x4 microtile) ----------------
#define EPI_BIAS 0
#define EPI_BIAS_RELU 1
#define EPI_DEG_GELU 2
#define EPI_NONE 3

__device__ __forceinline__ float gelu_exact(float x) {
    return 0.5f * x * (1.0f + erff(x * 0.70710678118654752f));
}

template<int EPI>
__global__ __launch_bounds__(256) void gemm_f32(
        const float* __restrict__ A, const float* __restrict__ B,
        const float* __restrict__ bias, const int* __restrict__ deg,
        float* __restrict__ C, int M, int N, int K) {
    const int BM = 64, BN = 64, BK = 16;
    __shared__ float As[BK][BM + 1];
    __shared__ float Bs[BK][BN + 1];
    int tid = threadIdx.x;
    int m0 = blockIdx.y * BM;
    int n0 = blockIdx.x * BN;
    int ty = tid >> 4, tx = tid & 15;
    int arow = tid >> 2;           // 0..63
    int akk  = (tid & 3) * 4;      // 0,4,8,12
    int bkk  = tid >> 4;           // 0..15
    int bj   = (tid & 15) * 4;     // 0..60
    float acc[4][4] = {};
    for (int k0 = 0; k0 < K; k0 += BK) {
        int row = m0 + arow;
        if (row < M) {
            const float4 av = *reinterpret_cast<const float4*>(A + (size_t)row * K + k0 + akk);
            As[akk + 0][arow] = av.x; As[akk + 1][arow] = av.y;
            As[akk + 2][arow] = av.z; As[akk + 3][arow] = av.w;
        } else {
            As[akk + 0][arow] = 0.f; As[akk + 1][arow] = 0.f;
            As[akk + 2][arow] = 0.f; As[akk + 3][arow] = 0.f;
        }
#pragma unroll
        for (int j = 0; j < 4; j++) {
            int col = n0 + bj + j;
            Bs[bkk][bj + j] = (col < N) ? B[(size_t)(k0 + bkk) * N + col] : 0.f;
        }
        __syncthreads();
#pragma unroll
        for (int kk = 0; kk < BK; kk++) {
            float a[4], b[4];
#pragma unroll
            for (int i = 0; i < 4; i++) a[i] = As[kk][ty * 4 + i];
#pragma unroll
            for (int j = 0; j < 4; j++) b[j] = Bs[kk][tx * 4 + j];
#pragma unroll
            for (int i = 0; i < 4; i++)
#pragma unroll
                for (int j = 0; j < 4; j++)
                    acc[i][j] += a[i] * b[j];
        }
        __syncthreads();
    }
#pragma unroll
    for (int i = 0; i < 4; i++) {
        int row = m0 + ty * 4 + i;
        if (row >= M) continue;
#pragma unroll
        for (int j = 0; j < 4; j++) {
            int col = n0 + tx * 4 + j;
            if (col >= N) continue;
            float v = acc[i][j];
            if (EPI == EPI_BIAS)       { v += bias[col]; }
            else if (EPI == EPI_BIAS_RELU) { v += bias[col]; v = fmaxf(v, 0.f); }
            else if (EPI == EPI_DEG_GELU)  { v += (float)deg[row] * bias[col]; v = gelu_exact(v); }
            C[(size_t)row * N + col] = v;
        }
    }
}

// ---------------- CSR build (counting sort of edges by dst) ----------------
__global__ void count_deg(const int* __restrict__ dst, int* __restrict__ deg) {
    int e = blockIdx.x * blockDim.x + threadIdx.x;
    if (e < N_EDGES) atomicAdd(&deg[dst[e]], 1);
}

#define SCAN_THREADS 1024
__global__ void scan_offsets(const int* __restrict__ deg, int* __restrict__ offsets,
                             int* __restrict__ cursor, int n) {
    __shared__ int sums[SCAN_THREADS];
    int t = threadIdx.x;
    int chunk = (n + SCAN_THREADS - 1) / SCAN_THREADS;
    int start = t * chunk;
    int end = min(start + chunk, n);
    int s = 0;
    for (int i = start; i < end; i++) s += deg[i];
    sums[t] = s;
    __syncthreads();
    for (int off = 1; off < SCAN_THREADS; off <<= 1) {
        int v = (t >= off) ? sums[t - off] : 0;
        __syncthreads();
        sums[t] += v;
        __syncthreads();
    }
    int run = (t == 0) ? 0 : sums[t - 1];  // exclusive prefix
    for (int i = start; i < end; i++) {
        offsets[i] = run;
        cursor[i] = run;
        run += deg[i];
    }
    if (t == SCAN_THREADS - 1) offsets[n] = run;
}

__global__ void place_edges(const int* __restrict__ src, const int* __restrict__ dst,
                            const int* __restrict__ lab, int* __restrict__ cursor,
                            int* __restrict__ src_s, int* __restrict__ lab_s) {
    int e = blockIdx.x * blockDim.x + threadIdx.x;
    if (e < N_EDGES) {
        int pos = atomicAdd(&cursor[dst[e]], 1);
        src_s[pos] = src[e];
        lab_s[pos] = lab[e];
    }
}

// ---------------- per-etype projection: edge_emb[l] @ W1[256:384,:] + b1 ----------------
__global__ void etype_proj_kernel(const float* __restrict__ ee,   // [44,128]
                                  const float* __restrict__ W1ef, // [128,256]
                                  const float* __restrict__ b1,   // [256]
                                  float* __restrict__ out) {      // [44,256]
    int et = blockIdx.x;
    int c = threadIdx.x;  // 256
    float s = b1[c];
    for (int k = 0; k < DMODEL; k++)
        s += ee[et * DMODEL + k] * W1ef[k * 256 + c];
    out[et * 256 + c] = s;
}

// ---------------- edge aggregation: P[i] = sum_{e: dst=i} relu(Hd[i]+Hs[src]+etp[lab]) ----------------
__global__ __launch_bounds__(256) void edge_agg(
        const float* __restrict__ Hd, const float* __restrict__ Hs,
        const float* __restrict__ etp, const int* __restrict__ offsets,
        const int* __restrict__ src_s, const int* __restrict__ lab_s,
        float* __restrict__ P) {
    int i = blockIdx.x;
    int c = threadIdx.x;  // 256
    float hd = Hd[(size_t)i * 256 + c];
    float acc = 0.f;
    int e0 = offsets[i], e1 = offsets[i + 1];
    for (int e = e0; e < e1; ++e) {
        int s = src_s[e];
        int lb = lab_s[e];
        float v = hd + Hs[(size_t)s * 256 + c] + etp[lb * 256 + c];
        acc += fmaxf(v, 0.f);
    }
    P[(size_t)i * 256 + c] = acc;
}

// ---------------- readout ----------------
__global__ void readout_scatter(const float* __restrict__ h, const int* __restrict__ vg,
                                const int* __restrict__ vs, float* __restrict__ sums,
                                int* __restrict__ cnt) {
    int m = blockIdx.x * 2 + (threadIdx.x >> 7);
    int c = threadIdx.x & 127;
    if (m >= N_MENTIONS) return;
    int node = vg[m];
    int v = vs[m];
    atomicAdd(&sums[(size_t)v * DMODEL + c], h[(size_t)node * DMODEL + c]);
    if (c == 0) atomicAdd(&cnt[v], 1);
}

__global__ void divide_kernel(float* __restrict__ sums, const int* __restrict__ cnt) {
    int v = blockIdx.x;
    int c = threadIdx.x;  // 128
    float d = (float)max(cnt[v], 1);
    sums[(size_t)v * DMODEL + c] /= d;
}

// ---------------- launcher ----------------
extern "C" void kernel_launch(void* const* d_in, const int* in_sizes, int n_in,
                              void* d_out, int out_size, void* d_ws, size_t ws_size,
                              hipStream_t stream) {
    const float* node_labels = (const float*)d_in[0];
    const int*   edges       = (const int*)d_in[1];
    const int*   edge_labels = (const int*)d_in[2];
    const int*   var_gather  = (const int*)d_in[3];
    const int*   var_scatter = (const int*)d_in[4];
    // d_in[5] labels (unused), d_in[6] num_vars (constant 20000)
    const float* enc_W0 = (const float*)d_in[7];
    const float* enc_b0 = (const float*)d_in[8];
    const float* enc_W1 = (const float*)d_in[9];
    const float* enc_b1 = (const float*)d_in[10];
    const float* edge_emb = (const float*)d_in[11];
    const float* mlp_W1 = (const float*)d_in[12];
    const float* mlp_b1 = (const float*)d_in[13];
    const float* mlp_W2 = (const float*)d_in[14];
    const float* mlp_b2 = (const float*)d_in[15];
    const float* dec_W0 = (const float*)d_in[16];
    const float* dec_b0 = (const float*)d_in[17];
    const float* dec_Wl = (const float*)d_in[18];
    const float* dec_bl = (const float*)d_in[19];
    float* out = (float*)d_out;

    char* ws = (char*)d_ws;
    size_t off = 0;
    auto alloc = [&](size_t bytes) -> void* {
        void* p = ws + off;
        off += (bytes + 255) & ~(size_t)255;
        return p;
    };
    float* h    = (float*)alloc((size_t)N_NODES * DMODEL * 4);
    float* Hd   = (float*)alloc((size_t)N_NODES * 256 * 4);
    float* Hs   = (float*)alloc((size_t)N_NODES * 256 * 4);
    float* P    = (float*)alloc((size_t)N_NODES * 256 * 4);
    float* etp  = (float*)alloc((size_t)N_ETYPES * 256 * 4);
    int* deg    = (int*)alloc((size_t)N_NODES * 4);
    int* offs   = (int*)alloc((size_t)(N_NODES + 1) * 4);
    int* cursor = (int*)alloc((size_t)N_NODES * 4);
    int* src_s  = (int*)alloc((size_t)N_EDGES * 4);
    int* lab_s  = (int*)alloc((size_t)N_EDGES * 4);
    float* vsum = (float*)alloc((size_t)N_VARS * DMODEL * 4);
    int* vcnt   = (int*)alloc((size_t)N_VARS * 4);
    float* dtmp = Hd;  // reuse (free by readout time)

    const int* e_src = edges;
    const int* e_dst = edges + N_EDGES;

    hipMemsetAsync(deg, 0, (size_t)N_NODES * 4, stream);
    hipMemsetAsync(vsum, 0, (size_t)N_VARS * DMODEL * 4, stream);
    hipMemsetAsync(vcnt, 0, (size_t)N_VARS * 4, stream);

    // CSR build (edges sorted by dst)
    count_deg<<<(N_EDGES + 255) / 256, 256, 0, stream>>>(e_dst, deg);
    scan_offsets<<<1, SCAN_THREADS, 0, stream>>>(deg, offs, cursor, N_NODES);
    place_edges<<<(N_EDGES + 255) / 256, 256, 0, stream>>>(e_src, e_dst, edge_labels, cursor,
                                                           src_s, lab_s);

    dim3 blk(256);
    auto grd = [](int M, int N) { return dim3((N + 63) / 64, (M + 63) / 64); };

    // encoder: h = relu(x @ W0 + b0) @ W1 + b1
    gemm_f32<EPI_BIAS_RELU><<<grd(N_NODES, DMODEL), blk, 0, stream>>>(
        node_labels, enc_W0, enc_b0, nullptr, Hd, N_NODES, DMODEL, IN_DIM);
    gemm_f32<EPI_BIAS><<<grd(N_NODES, DMODEL), blk, 0, stream>>>(
        Hd, enc_W1, enc_b1, nullptr, h, N_NODES, DMODEL, DMODEL);

    // message-passing layers
    for (int l = 0; l < N_LAYERS; ++l) {
        const float* W1 = mlp_W1 + (size_t)l * 384 * 256;
        const float* b1 = mlp_b1 + (size_t)l * 256;
        const float* W2 = mlp_W2 + (size_t)l * 256 * DMODEL;
        const float* b2 = mlp_b2 + (size_t)l * DMODEL;
        const float* ee = edge_emb + (size_t)l * N_ETYPES * DMODEL;

        etype_proj_kernel<<<N_ETYPES, 256, 0, stream>>>(ee, W1 + 256 * 256, b1, etp);
        gemm_f32<EPI_NONE><<<grd(N_NODES, 256), blk, 0, stream>>>(
            h, W1, nullptr, nullptr, Hd, N_NODES, 256, DMODEL);
        gemm_f32<EPI_NONE><<<grd(N_NODES, 256), blk, 0, stream>>>(
            h, W1 + 128 * 256, nullptr, nullptr, Hs, N_NODES, 256, DMODEL);
        edge_agg<<<N_NODES, 256, 0, stream>>>(Hd, Hs, etp, offs, src_s, lab_s, P);
        gemm_f32<EPI_DEG_GELU><<<grd(N_NODES, DMODEL), blk, 0, stream>>>(
            P, W2, b2, deg, h, N_NODES, DMODEL, 256);
    }

    // readout: scatter-mean into variables
    readout_scatter<<<(N_MENTIONS + 1) / 2, 256, 0, stream>>>(h, var_gather, var_scatter, vsum, vcnt);
    divide_kernel<<<N_VARS, DMODEL, 0, stream>>>(vsum, vcnt);

    // decoder
    gemm_f32<EPI_BIAS_RELU><<<grd(N_VARS, DMODEL), blk, 0, stream>>>(
        vsum, dec_W0, dec_b0, nullptr, dtmp, N_VARS, DMODEL, DMODEL);
    gemm_f32<EPI_BIAS><<<grd(N_VARS, OUT_DIM), blk, 0, stream>>>(
        dtmp, dec_Wl, dec_bl, nullptr, out, N_VARS, OUT_DIM, DMODEL);
}

// Round 4
// 1919.110 us; speedup vs baseline: 1.8656x; 1.8656x over previous
//
#include <hip/hip_runtime.h>
#include <math.h>

#define N_NODES 50000
#define N_EDGES 600000
#define IN_DIM 64
#define DMODEL 128
#define N_LAYERS 8
#define N_ETYPES 44
#define N_MENTIONS 100000
#define N_VARS 20000
#define OUT_DIM 100

#define EPI_BIAS 0
#define EPI_BIAS_RELU 1
#define EPI_DEG_GELU 2
#define EPI_NONE 3

#define SCL  6.103515625e-05f   /* 2^-14: pre-scale A into f16 range (|h| can reach ~1e7) */
#define SCLI 16384.0f

typedef _Float16 f16x8 __attribute__((ext_vector_type(8)));
typedef float f32x4 __attribute__((ext_vector_type(4)));

__device__ __forceinline__ float gelu_exact(float x) {
    return 0.5f * x * (1.0f + erff(x * 0.70710678118654752f));
}

// ---------------- weight prep: transpose [K,N]->[Npad,K] and split fp32 -> f16 hi+lo ----------
// cat==1: out n in [0,512) maps to src rows k (n<256) / k+128 (n>=256), col n&255 (for fused W1).
__global__ void wprep(const float* __restrict__ src, _Float16* __restrict__ dhi,
                      _Float16* __restrict__ dlo, int K, int Nsrc, int Npad,
                      long srcLS, long dstLS, int cat) {
    __shared__ float sh[16][17];
    int z = blockIdx.z;
    src += (size_t)z * srcLS;
    dhi += (size_t)z * dstLS;
    dlo += (size_t)z * dstLS;
    int n0 = blockIdx.x * 16, k0 = blockIdx.y * 16;
    int tx = threadIdx.x, ty = threadIdx.y;
    int nr = n0 + tx, kr = k0 + ty;
    float v;
    if (cat) {
        int half = nr >> 8;
        int nc = nr & 255;
        v = src[(size_t)(kr + half * 128) * 256 + nc];
    } else {
        v = (nr < Nsrc) ? src[(size_t)kr * Nsrc + nr] : 0.f;
    }
    sh[ty][tx] = v;
    __syncthreads();
    float x = sh[tx][ty];
    int n = n0 + ty, k = k0 + tx;
    _Float16 hi = (_Float16)x;
    float lo = x - (float)hi;
    dhi[(size_t)n * K + k] = hi;
    dlo[(size_t)n * K + k] = (_Float16)lo;
}

// ---------------- 3xF16 MFMA GEMM: C = A(fp32) @ B + epilogue ----------------
// A [M,K] fp32 (split to hi/lo f16 in-kernel, scaled by 2^-14); B pre-split [Npad,K] f16 hi/lo.
// 64x64 tile, BK=32, 256 thr = 4 waves (2x2), each wave 32x32 via 2x2 mfma_16x16x32 tiles.
template<int EPI>
__global__ __launch_bounds__(256) void gemm3h(
        const float* __restrict__ A, const _Float16* __restrict__ Bh,
        const _Float16* __restrict__ Bl, const float* __restrict__ bias,
        const int* __restrict__ deg, float* __restrict__ C,
        int M, int N, int K, int ldC) {
    // LDS stride 56 f16 (112 B): 16B-aligned rows, 2-way-max bank aliasing (free)
    __shared__ _Float16 Ah[64 * 56], Al[64 * 56], Bsh[64 * 56], Bsl[64 * 56];
    int t = threadIdx.x;
    int m0 = blockIdx.y * 64, n0 = blockIdx.x * 64;
    int ar = t >> 2, ac = (t & 3) * 8;           // A staging: 4 thr/row, 8 floats each
    int btt = t & 127, br = btt >> 1, bc = (btt & 1) * 16;  // B staging: 128 thr per array
    const _Float16* Bsrc = (t < 128) ? Bh : Bl;
    _Float16* Bdst = (t < 128) ? Bsh : Bsl;
    int lane = t & 63, wid = t >> 6;
    int wm = (wid >> 1) * 32, wn = (wid & 1) * 32;
    int quad = lane >> 4, l15 = lane & 15;
    f32x4 acc[2][2] = {};
    bool arow_ok = (m0 + ar) < M;
    const float* Aptr = A + (size_t)(m0 + ar) * K + ac;
    const _Float16* Bptr = Bsrc + (size_t)(n0 + br) * K + bc;

    for (int k0 = 0; k0 < K; k0 += 32) {
        float4 v0 = {0, 0, 0, 0}, v1 = {0, 0, 0, 0};
        if (arow_ok) {
            v0 = *(const float4*)(Aptr + k0);
            v1 = *(const float4*)(Aptr + k0 + 4);
        }
        f16x8 hv, lv;
        float xs[8] = {v0.x, v0.y, v0.z, v0.w, v1.x, v1.y, v1.z, v1.w};
#pragma unroll
        for (int j = 0; j < 8; j++) {
            float s = xs[j] * SCL;
            _Float16 h = (_Float16)s;
            hv[j] = h;
            lv[j] = (_Float16)(s - (float)h);
        }
        *(f16x8*)&Ah[ar * 56 + ac] = hv;
        *(f16x8*)&Al[ar * 56 + ac] = lv;
        f16x8 b0 = *(const f16x8*)(Bptr + k0);
        f16x8 b1v = *(const f16x8*)(Bptr + k0 + 8);
        *(f16x8*)&Bdst[br * 56 + bc] = b0;
        *(f16x8*)&Bdst[br * 56 + bc + 8] = b1v;
        __syncthreads();

        f16x8 afh[2], afl[2], bfh[2], bfl[2];
#pragma unroll
        for (int i = 0; i < 2; i++) {
            int am = (wm + i * 16 + l15) * 56 + quad * 8;
            afh[i] = *(const f16x8*)&Ah[am];
            afl[i] = *(const f16x8*)&Al[am];
            int bn = (wn + i * 16 + l15) * 56 + quad * 8;
            bfh[i] = *(const f16x8*)&Bsh[bn];
            bfl[i] = *(const f16x8*)&Bsl[bn];
        }
#pragma unroll
        for (int i = 0; i < 2; i++)
#pragma unroll
            for (int j = 0; j < 2; j++) {
                acc[i][j] = __builtin_amdgcn_mfma_f32_16x16x32_f16(afh[i], bfh[j], acc[i][j], 0, 0, 0);
                acc[i][j] = __builtin_amdgcn_mfma_f32_16x16x32_f16(afh[i], bfl[j], acc[i][j], 0, 0, 0);
                acc[i][j] = __builtin_amdgcn_mfma_f32_16x16x32_f16(afl[i], bfh[j], acc[i][j], 0, 0, 0);
            }
        __syncthreads();
    }

#pragma unroll
    for (int i = 0; i < 2; i++) {
        int rowb = m0 + wm + i * 16 + quad * 4;
#pragma unroll
        for (int j = 0; j < 2; j++) {
            int col = n0 + wn + j * 16 + l15;
            if (col >= N) continue;
#pragma unroll
            for (int r = 0; r < 4; r++) {
                int row = rowb + r;
                if (row >= M) continue;
                float v = acc[i][j][r] * SCLI;
                if (EPI == EPI_BIAS) { v += bias[col]; }
                else if (EPI == EPI_BIAS_RELU) { v += bias[col]; v = fmaxf(v, 0.f); }
                else if (EPI == EPI_DEG_GELU) { v += (float)deg[row] * bias[col]; v = gelu_exact(v); }
                C[(size_t)row * ldC + col] = v;
            }
        }
    }
}

// ---------------- CSR build (counting sort of edges by dst) ----------------
__global__ void count_deg(const int* __restrict__ dst, int* __restrict__ deg) {
    int e = blockIdx.x * blockDim.x + threadIdx.x;
    if (e < N_EDGES) atomicAdd(&deg[dst[e]], 1);
}

#define SCAN_THREADS 1024
__global__ void scan_offsets(const int* __restrict__ deg, int* __restrict__ offsets,
                             int* __restrict__ cursor, int n) {
    __shared__ int sums[SCAN_THREADS];
    int t = threadIdx.x;
    int chunk = (n + SCAN_THREADS - 1) / SCAN_THREADS;
    int start = t * chunk;
    int end = min(start + chunk, n);
    int s = 0;
    for (int i = start; i < end; i++) s += deg[i];
    sums[t] = s;
    __syncthreads();
    for (int off = 1; off < SCAN_THREADS; off <<= 1) {
        int v = (t >= off) ? sums[t - off] : 0;
        __syncthreads();
        sums[t] += v;
        __syncthreads();
    }
    int run = (t == 0) ? 0 : sums[t - 1];
    for (int i = start; i < end; i++) {
        offsets[i] = run;
        cursor[i] = run;
        run += deg[i];
    }
    if (t == SCAN_THREADS - 1) offsets[n] = run;
}

__global__ void place_edges(const int* __restrict__ src, const int* __restrict__ dst,
                            const int* __restrict__ lab, int* __restrict__ cursor,
                            int* __restrict__ src_s, int* __restrict__ lab_s) {
    int e = blockIdx.x * blockDim.x + threadIdx.x;
    if (e < N_EDGES) {
        int pos = atomicAdd(&cursor[dst[e]], 1);
        src_s[pos] = src[e];
        lab_s[pos] = lab[e];
    }
}

// ---------------- per-etype projection (fp32, tiny): edge_emb[l] @ W1[256:384,:] + b1 ----------
__global__ void etype_proj_kernel(const float* __restrict__ ee, const float* __restrict__ W1ef,
                                  const float* __restrict__ b1, float* __restrict__ out) {
    int et = blockIdx.x;
    int c = threadIdx.x;  // 256
    float s = b1[c];
    for (int k = 0; k < DMODEL; k++)
        s += ee[et * DMODEL + k] * W1ef[k * 256 + c];
    out[et * 256 + c] = s;
}

// ---------------- edge aggregation: P[i] = sum_{e: dst=i} relu(Hd[i]+Hs[src]+etp[lab]) ---------
// HH = fused W1 output [N_NODES, 512]: cols 0..255 = Hd, 256..511 = Hs.
// 4 waves/block, each owns every-4th edge; threads hold float4 channel chunks.
__global__ __launch_bounds__(256) void edge_agg(
        const float* __restrict__ HH, const float* __restrict__ etp,
        const int* __restrict__ offsets, const int* __restrict__ src_s,
        const int* __restrict__ lab_s, float* __restrict__ P) {
    int i = blockIdx.x;
    int g = threadIdx.x >> 6, tl = threadIdx.x & 63;
    int c4 = tl * 4;
    float4 hd = *(const float4*)&HH[(size_t)i * 512 + c4];
    float4 acc = {0.f, 0.f, 0.f, 0.f};
    int e0 = offsets[i], e1 = offsets[i + 1];
    for (int e = e0 + g; e < e1; e += 4) {
        int s = src_s[e], lb = lab_s[e];
        float4 hs = *(const float4*)&HH[(size_t)s * 512 + 256 + c4];
        float4 et = *(const float4*)&etp[lb * 256 + c4];
        acc.x += fmaxf(hd.x + hs.x + et.x, 0.f);
        acc.y += fmaxf(hd.y + hs.y + et.y, 0.f);
        acc.z += fmaxf(hd.z + hs.z + et.z, 0.f);
        acc.w += fmaxf(hd.w + hs.w + et.w, 0.f);
    }
    __shared__ float4 red[4][64];
    red[g][tl] = acc;
    __syncthreads();
    if (g == 0) {
        float4 a = red[0][tl], b = red[1][tl], c = red[2][tl], d = red[3][tl];
        float4 s;
        s.x = (a.x + b.x) + (c.x + d.x);
        s.y = (a.y + b.y) + (c.y + d.y);
        s.z = (a.z + b.z) + (c.z + d.z);
        s.w = (a.w + b.w) + (c.w + d.w);
        *(float4*)&P[(size_t)i * 256 + c4] = s;
    }
}

// ---------------- readout ----------------
__global__ void readout_scatter(const float* __restrict__ h, const int* __restrict__ vg,
                                const int* __restrict__ vs, float* __restrict__ sums,
                                int* __restrict__ cnt) {
    int m = blockIdx.x * 2 + (threadIdx.x >> 7);
    int c = threadIdx.x & 127;
    if (m >= N_MENTIONS) return;
    int node = vg[m];
    int v = vs[m];
    atomicAdd(&sums[(size_t)v * DMODEL + c], h[(size_t)node * DMODEL + c]);
    if (c == 0) atomicAdd(&cnt[v], 1);
}

__global__ void divide_kernel(float* __restrict__ sums, const int* __restrict__ cnt) {
    int v = blockIdx.x;
    int c = threadIdx.x;  // 128
    float d = (float)max(cnt[v], 1);
    sums[(size_t)v * DMODEL + c] /= d;
}

// ---------------- launcher ----------------
extern "C" void kernel_launch(void* const* d_in, const int* in_sizes, int n_in,
                              void* d_out, int out_size, void* d_ws, size_t ws_size,
                              hipStream_t stream) {
    const float* node_labels = (const float*)d_in[0];
    const int*   edges       = (const int*)d_in[1];
    const int*   edge_labels = (const int*)d_in[2];
    const int*   var_gather  = (const int*)d_in[3];
    const int*   var_scatter = (const int*)d_in[4];
    const float* enc_W0 = (const float*)d_in[7];
    const float* enc_b0 = (const float*)d_in[8];
    const float* enc_W1 = (const float*)d_in[9];
    const float* enc_b1 = (const float*)d_in[10];
    const float* edge_emb = (const float*)d_in[11];
    const float* mlp_W1 = (const float*)d_in[12];
    const float* mlp_b1 = (const float*)d_in[13];
    const float* mlp_W2 = (const float*)d_in[14];
    const float* mlp_b2 = (const float*)d_in[15];
    const float* dec_W0 = (const float*)d_in[16];
    const float* dec_b0 = (const float*)d_in[17];
    const float* dec_Wl = (const float*)d_in[18];
    const float* dec_bl = (const float*)d_in[19];
    float* out = (float*)d_out;

    char* ws = (char*)d_ws;
    size_t off = 0;
    auto alloc = [&](size_t bytes) -> void* {
        void* p = ws + off;
        off += (bytes + 255) & ~(size_t)255;
        return p;
    };
    float* h    = (float*)alloc((size_t)N_NODES * DMODEL * 4);       // 25.6 MB
    float* HH   = (float*)alloc((size_t)N_NODES * 512 * 4);          // 102.4 MB (also vsum/vcnt/dtmp later)
    float* P    = (float*)alloc((size_t)N_NODES * 256 * 4);          // 51.2 MB (also henc)
    float* etp  = (float*)alloc((size_t)N_ETYPES * 256 * 4);
    int* deg    = (int*)alloc((size_t)N_NODES * 4);
    int* offs   = (int*)alloc((size_t)(N_NODES + 1) * 4);
    int* cursor = (int*)alloc((size_t)N_NODES * 4);
    int* src_s  = (int*)alloc((size_t)N_EDGES * 4);
    int* lab_s  = (int*)alloc((size_t)N_EDGES * 4);
    _Float16* W1t_h = (_Float16*)alloc((size_t)N_LAYERS * 512 * 128 * 2);
    _Float16* W1t_l = (_Float16*)alloc((size_t)N_LAYERS * 512 * 128 * 2);
    _Float16* W2t_h = (_Float16*)alloc((size_t)N_LAYERS * 128 * 256 * 2);
    _Float16* W2t_l = (_Float16*)alloc((size_t)N_LAYERS * 128 * 256 * 2);
    _Float16* e0h = (_Float16*)alloc(128 * 64 * 2);
    _Float16* e0l = (_Float16*)alloc(128 * 64 * 2);
    _Float16* e1h = (_Float16*)alloc(128 * 128 * 2);
    _Float16* e1l = (_Float16*)alloc(128 * 128 * 2);
    _Float16* d0h = (_Float16*)alloc(128 * 128 * 2);
    _Float16* d0l = (_Float16*)alloc(128 * 128 * 2);
    _Float16* dlh = (_Float16*)alloc(128 * 128 * 2);
    _Float16* dll = (_Float16*)alloc(128 * 128 * 2);
    // overlap late-phase buffers into HH (free after last edge_agg):
    float* vsum = HH;
    int*   vcnt = (int*)(HH + (size_t)N_VARS * DMODEL);
    float* dtmp = HH + (size_t)N_VARS * DMODEL + ((N_VARS + 63) & ~63);
    float* henc = P;

    const int* e_src = edges;
    const int* e_dst = edges + N_EDGES;

    hipMemsetAsync(deg, 0, (size_t)N_NODES * 4, stream);

    // CSR build
    count_deg<<<(N_EDGES + 255) / 256, 256, 0, stream>>>(e_dst, deg);
    scan_offsets<<<1, SCAN_THREADS, 0, stream>>>(deg, offs, cursor, N_NODES);
    place_edges<<<(N_EDGES + 255) / 256, 256, 0, stream>>>(e_src, e_dst, edge_labels, cursor,
                                                           src_s, lab_s);

    // weight prep (transpose + hi/lo split)
    dim3 pb(16, 16);
    wprep<<<dim3(32, 8, N_LAYERS), pb, 0, stream>>>(mlp_W1, W1t_h, W1t_l, 128, 512, 512,
                                                    (long)384 * 256, (long)512 * 128, 1);
    wprep<<<dim3(8, 16, N_LAYERS), pb, 0, stream>>>(mlp_W2, W2t_h, W2t_l, 256, 128, 128,
                                                    (long)256 * 128, (long)128 * 256, 0);
    wprep<<<dim3(8, 4, 1), pb, 0, stream>>>(enc_W0, e0h, e0l, 64, 128, 128, 0, 0, 0);
    wprep<<<dim3(8, 8, 1), pb, 0, stream>>>(enc_W1, e1h, e1l, 128, 128, 128, 0, 0, 0);
    wprep<<<dim3(8, 8, 1), pb, 0, stream>>>(dec_W0, d0h, d0l, 128, 128, 128, 0, 0, 0);
    wprep<<<dim3(8, 8, 1), pb, 0, stream>>>(dec_Wl, dlh, dll, 128, 100, 128, 0, 0, 0);

    dim3 blk(256);
    const int MT_N = (N_NODES + 63) / 64;   // 782
    const int MT_V = (N_VARS + 63) / 64;    // 313

    // encoder
    gemm3h<EPI_BIAS_RELU><<<dim3(2, MT_N), blk, 0, stream>>>(
        node_labels, e0h, e0l, enc_b0, nullptr, henc, N_NODES, 128, 64, 128);
    gemm3h<EPI_BIAS><<<dim3(2, MT_N), blk, 0, stream>>>(
        henc, e1h, e1l, enc_b1, nullptr, h, N_NODES, 128, 128, 128);

    // message-passing layers
    for (int l = 0; l < N_LAYERS; ++l) {
        const float* W1 = mlp_W1 + (size_t)l * 384 * 256;
        const float* b1 = mlp_b1 + (size_t)l * 256;
        const float* b2 = mlp_b2 + (size_t)l * DMODEL;
        const float* ee = edge_emb + (size_t)l * N_ETYPES * DMODEL;

        etype_proj_kernel<<<N_ETYPES, 256, 0, stream>>>(ee, W1 + 256 * 256, b1, etp);
        gemm3h<EPI_NONE><<<dim3(8, MT_N), blk, 0, stream>>>(
            h, W1t_h + (size_t)l * 512 * 128, W1t_l + (size_t)l * 512 * 128,
            nullptr, nullptr, HH, N_NODES, 512, 128, 512);
        edge_agg<<<N_NODES, blk, 0, stream>>>(HH, etp, offs, src_s, lab_s, P);
        gemm3h<EPI_DEG_GELU><<<dim3(2, MT_N), blk, 0, stream>>>(
            P, W2t_h + (size_t)l * 128 * 256, W2t_l + (size_t)l * 128 * 256,
            b2, deg, h, N_NODES, 128, 256, 128);
    }

    // readout: scatter-mean into variables (vsum/vcnt live in HH, free now)
    hipMemsetAsync(vsum, 0, (size_t)N_VARS * DMODEL * 4, stream);
    hipMemsetAsync(vcnt, 0, (size_t)N_VARS * 4, stream);
    readout_scatter<<<(N_MENTIONS + 1) / 2, 256, 0, stream>>>(h, var_gather, var_scatter, vsum, vcnt);
    divide_kernel<<<N_VARS, DMODEL, 0, stream>>>(vsum, vcnt);

    // decoder
    gemm3h<EPI_BIAS_RELU><<<dim3(2, MT_V), blk, 0, stream>>>(
        vsum, d0h, d0l, dec_b0, nullptr, dtmp, N_VARS, 128, 128, 128);
    gemm3h<EPI_BIAS><<<dim3(2, MT_V), blk, 0, stream>>>(
        dtmp, dlh, dll, dec_bl, nullptr, out, N_VARS, OUT_DIM, 128, OUT_DIM);
}

// Round 5
// 1770.673 us; speedup vs baseline: 2.0219x; 1.0838x over previous
//
#include <hip/hip_runtime.h>
#include <math.h>

#define N_NODES 50000
#define N_EDGES 600000
#define IN_DIM 64
#define DMODEL 128
#define N_LAYERS 8
#define N_ETYPES 44
#define N_MENTIONS 100000
#define N_VARS 20000
#define OUT_DIM 100

#define EPI_BIAS 0
#define EPI_BIAS_RELU 1
#define EPI_DEG_GELU 2
#define EPI_NONE 3

#define SCL  6.103515625e-05f   /* 2^-14: pre-scale into f16 range (|h| can reach ~1e7) */
#define SCLI 16384.0f

typedef _Float16 f16x8 __attribute__((ext_vector_type(8)));
typedef _Float16 f16x4 __attribute__((ext_vector_type(4)));
typedef float f32x4 __attribute__((ext_vector_type(4)));

__device__ __forceinline__ float gelu_exact(float x) {
    return 0.5f * x * (1.0f + erff(x * 0.70710678118654752f));
}

// ---------------- weight prep: transpose [K,N]->[Npad,K] and split fp32 -> f16 hi+lo ----------
__global__ void wprep(const float* __restrict__ src, _Float16* __restrict__ dhi,
                      _Float16* __restrict__ dlo, int K, int Nsrc, int Npad,
                      long srcLS, long dstLS, int cat) {
    __shared__ float sh[16][17];
    int z = blockIdx.z;
    src += (size_t)z * srcLS;
    dhi += (size_t)z * dstLS;
    dlo += (size_t)z * dstLS;
    int n0 = blockIdx.x * 16, k0 = blockIdx.y * 16;
    int tx = threadIdx.x, ty = threadIdx.y;
    int nr = n0 + tx, kr = k0 + ty;
    float v;
    if (cat) {
        int half = nr >> 8;
        int nc = nr & 255;
        v = src[(size_t)(kr + half * 128) * 256 + nc];
    } else {
        v = (nr < Nsrc) ? src[(size_t)kr * Nsrc + nr] : 0.f;
    }
    sh[ty][tx] = v;
    __syncthreads();
    float x = sh[tx][ty];
    int n = n0 + ty, k = k0 + tx;
    _Float16 hi = (_Float16)x;
    float lo = x - (float)hi;
    dhi[(size_t)n * K + k] = hi;
    dlo[(size_t)n * K + k] = (_Float16)lo;
}

// ---------------- 3xF16 MFMA GEMM ----------------
// A either fp32 [M,K] (split+scale in-kernel) or pre-split/pre-scaled f16 hi/lo [M,K].
// B pre-split [Npad,K] f16 hi/lo. 64x64 tile, BK=32, 256 thr = 4 waves, 2x2 mfma tiles each.
// OSPLIT: epilogue writes pre-scaled f16 hi/lo pair (for next ASPLIT consumer) instead of fp32.
template<int EPI, int ASPLIT, int OSPLIT>
__global__ __launch_bounds__(256) void gemm3h(
        const float* __restrict__ A, const _Float16* __restrict__ Ahi,
        const _Float16* __restrict__ Alo,
        const _Float16* __restrict__ Bh, const _Float16* __restrict__ Bl,
        const float* __restrict__ bias, const int* __restrict__ deg,
        float* __restrict__ C, _Float16* __restrict__ Chi, _Float16* __restrict__ Clo,
        int M, int N, int K, int ldC) {
    __shared__ _Float16 Ah[64 * 56], Al[64 * 56], Bsh[64 * 56], Bsl[64 * 56];
    int t = threadIdx.x;
    int m0 = blockIdx.y * 64, n0 = blockIdx.x * 64;
    int ar = t >> 2, ac = (t & 3) * 8;
    int btt = t & 127, br = btt >> 1, bc = (btt & 1) * 16;
    const _Float16* Bsrc = (t < 128) ? Bh : Bl;
    _Float16* Bdst = (t < 128) ? Bsh : Bsl;
    int lane = t & 63, wid = t >> 6;
    int wm = (wid >> 1) * 32, wn = (wid & 1) * 32;
    int quad = lane >> 4, l15 = lane & 15;
    f32x4 acc[2][2] = {};
    bool arow_ok = (m0 + ar) < M;
    const float* Aptr = ASPLIT ? nullptr : (A + (size_t)(m0 + ar) * K + ac);
    const _Float16* Ahp = ASPLIT ? (Ahi + (size_t)(m0 + ar) * K + ac) : nullptr;
    const _Float16* Alp = ASPLIT ? (Alo + (size_t)(m0 + ar) * K + ac) : nullptr;
    const _Float16* Bptr = Bsrc + (size_t)(n0 + br) * K + bc;

    for (int k0 = 0; k0 < K; k0 += 32) {
        f16x8 hv = {}, lv = {};
        if (ASPLIT) {
            if (arow_ok) {
                hv = *(const f16x8*)(Ahp + k0);
                lv = *(const f16x8*)(Alp + k0);
            }
        } else {
            float4 v0 = {0, 0, 0, 0}, v1 = {0, 0, 0, 0};
            if (arow_ok) {
                v0 = *(const float4*)(Aptr + k0);
                v1 = *(const float4*)(Aptr + k0 + 4);
            }
            float xs[8] = {v0.x, v0.y, v0.z, v0.w, v1.x, v1.y, v1.z, v1.w};
#pragma unroll
            for (int j = 0; j < 8; j++) {
                float s = xs[j] * SCL;
                _Float16 h = (_Float16)s;
                hv[j] = h;
                lv[j] = (_Float16)(s - (float)h);
            }
        }
        *(f16x8*)&Ah[ar * 56 + ac] = hv;
        *(f16x8*)&Al[ar * 56 + ac] = lv;
        f16x8 b0 = *(const f16x8*)(Bptr + k0);
        f16x8 b1v = *(const f16x8*)(Bptr + k0 + 8);
        *(f16x8*)&Bdst[br * 56 + bc] = b0;
        *(f16x8*)&Bdst[br * 56 + bc + 8] = b1v;
        __syncthreads();

        f16x8 afh[2], afl[2], bfh[2], bfl[2];
#pragma unroll
        for (int i = 0; i < 2; i++) {
            int am = (wm + i * 16 + l15) * 56 + quad * 8;
            afh[i] = *(const f16x8*)&Ah[am];
            afl[i] = *(const f16x8*)&Al[am];
            int bn = (wn + i * 16 + l15) * 56 + quad * 8;
            bfh[i] = *(const f16x8*)&Bsh[bn];
            bfl[i] = *(const f16x8*)&Bsl[bn];
        }
#pragma unroll
        for (int i = 0; i < 2; i++)
#pragma unroll
            for (int j = 0; j < 2; j++) {
                acc[i][j] = __builtin_amdgcn_mfma_f32_16x16x32_f16(afh[i], bfh[j], acc[i][j], 0, 0, 0);
                acc[i][j] = __builtin_amdgcn_mfma_f32_16x16x32_f16(afh[i], bfl[j], acc[i][j], 0, 0, 0);
                acc[i][j] = __builtin_amdgcn_mfma_f32_16x16x32_f16(afl[i], bfh[j], acc[i][j], 0, 0, 0);
            }
        __syncthreads();
    }

#pragma unroll
    for (int i = 0; i < 2; i++) {
        int rowb = m0 + wm + i * 16 + quad * 4;
#pragma unroll
        for (int j = 0; j < 2; j++) {
            int col = n0 + wn + j * 16 + l15;
            if (col >= N) continue;
#pragma unroll
            for (int r = 0; r < 4; r++) {
                int row = rowb + r;
                if (row >= M) continue;
                float v = acc[i][j][r] * SCLI;
                if (EPI == EPI_BIAS) { v += bias[col]; }
                else if (EPI == EPI_BIAS_RELU) { v += bias[col]; v = fmaxf(v, 0.f); }
                else if (EPI == EPI_DEG_GELU) { v += (float)deg[row] * bias[col]; v = gelu_exact(v); }
                size_t idx = (size_t)row * ldC + col;
                if (OSPLIT) {
                    float s = v * SCL;
                    _Float16 h = (_Float16)s;
                    Chi[idx] = h;
                    Clo[idx] = (_Float16)(s - (float)h);
                } else {
                    C[idx] = v;
                }
            }
        }
    }
}

// ---------------- CSR build ----------------
__global__ void count_deg(const int* __restrict__ dst, int* __restrict__ deg) {
    int e = blockIdx.x * blockDim.x + threadIdx.x;
    if (e < N_EDGES) atomicAdd(&deg[dst[e]], 1);
}

#define SCAN_B 1024
#define SCAN_NB ((N_NODES + SCAN_B - 1) / SCAN_B)

__global__ void scan_local(const int* __restrict__ deg, int* __restrict__ offs,
                           int* __restrict__ bsum, int n) {
    __shared__ int sh[SCAN_B];
    int t = threadIdx.x;
    int i = blockIdx.x * SCAN_B + t;
    int v = (i < n) ? deg[i] : 0;
    sh[t] = v;
    __syncthreads();
    for (int o = 1; o < SCAN_B; o <<= 1) {
        int u = (t >= o) ? sh[t - o] : 0;
        __syncthreads();
        sh[t] += u;
        __syncthreads();
    }
    if (i < n) offs[i] = sh[t] - v;  // local exclusive
    if (t == SCAN_B - 1) bsum[blockIdx.x] = sh[t];
}

__global__ void scan_block(int* __restrict__ bsum, int nb) {
    __shared__ int sh[64];
    int t = threadIdx.x;
    int v = (t < nb) ? bsum[t] : 0;
    sh[t] = v;
    __syncthreads();
    for (int o = 1; o < 64; o <<= 1) {
        int u = (t >= o) ? sh[t - o] : 0;
        __syncthreads();
        sh[t] += u;
        __syncthreads();
    }
    if (t < nb) bsum[t] = sh[t] - v;  // exclusive base
}

__global__ void scan_final(int* __restrict__ offs, const int* __restrict__ bsum,
                           int* __restrict__ cursor, int n, int total) {
    int i = blockIdx.x * SCAN_B + threadIdx.x;
    if (i < n) {
        int o = offs[i] + bsum[blockIdx.x];
        offs[i] = o;
        cursor[i] = o;
    }
    if (i == n) offs[n] = total;
}

__global__ void place_edges(const int* __restrict__ src, const int* __restrict__ dst,
                            const int* __restrict__ lab, int* __restrict__ cursor,
                            int* __restrict__ src_s, int* __restrict__ lab_s) {
    int e = blockIdx.x * blockDim.x + threadIdx.x;
    if (e < N_EDGES) {
        int pos = atomicAdd(&cursor[dst[e]], 1);
        src_s[pos] = src[e];
        lab_s[pos] = lab[e];
    }
}

// ---------------- per-etype projection (tiny fp32) ----------------
__global__ void etype_proj_kernel(const float* __restrict__ ee, const float* __restrict__ W1ef,
                                  const float* __restrict__ b1, float* __restrict__ out) {
    int et = blockIdx.x;
    int c = threadIdx.x;  // 256
    float s = b1[c];
    for (int k = 0; k < DMODEL; k++)
        s += ee[et * DMODEL + k] * W1ef[k * 256 + c];
    out[et * 256 + c] = s;
}

// ---------------- edge aggregation ----------------
// HH [N,512] fp32: cols 0..255 = Hd, 256..511 = Hs. Output pre-scaled f16 hi/lo pair.
// 4 waves/block each own every-4th edge, unrolled x2 for 2 gathers in flight.
__global__ __launch_bounds__(256) void edge_agg(
        const float* __restrict__ HH, const float* __restrict__ etp,
        const int* __restrict__ offsets, const int* __restrict__ src_s,
        const int* __restrict__ lab_s, _Float16* __restrict__ Phi,
        _Float16* __restrict__ Plo) {
    int i = blockIdx.x;
    int g = threadIdx.x >> 6, tl = threadIdx.x & 63;
    int c4 = tl * 4;
    float4 hd = *(const float4*)&HH[(size_t)i * 512 + c4];
    float4 acc = {0.f, 0.f, 0.f, 0.f};
    int e0 = offsets[i], e1 = offsets[i + 1];
    int e = e0 + g;
    for (; e + 4 < e1; e += 8) {
        int s0 = src_s[e], l0 = lab_s[e];
        int s1 = src_s[e + 4], l1 = lab_s[e + 4];
        float4 hs0 = *(const float4*)&HH[(size_t)s0 * 512 + 256 + c4];
        float4 et0 = *(const float4*)&etp[l0 * 256 + c4];
        float4 hs1 = *(const float4*)&HH[(size_t)s1 * 512 + 256 + c4];
        float4 et1 = *(const float4*)&etp[l1 * 256 + c4];
        acc.x += fmaxf(hd.x + hs0.x + et0.x, 0.f) + fmaxf(hd.x + hs1.x + et1.x, 0.f);
        acc.y += fmaxf(hd.y + hs0.y + et0.y, 0.f) + fmaxf(hd.y + hs1.y + et1.y, 0.f);
        acc.z += fmaxf(hd.z + hs0.z + et0.z, 0.f) + fmaxf(hd.z + hs1.z + et1.z, 0.f);
        acc.w += fmaxf(hd.w + hs0.w + et0.w, 0.f) + fmaxf(hd.w + hs1.w + et1.w, 0.f);
    }
    if (e < e1) {
        int s0 = src_s[e], l0 = lab_s[e];
        float4 hs0 = *(const float4*)&HH[(size_t)s0 * 512 + 256 + c4];
        float4 et0 = *(const float4*)&etp[l0 * 256 + c4];
        acc.x += fmaxf(hd.x + hs0.x + et0.x, 0.f);
        acc.y += fmaxf(hd.y + hs0.y + et0.y, 0.f);
        acc.z += fmaxf(hd.z + hs0.z + et0.z, 0.f);
        acc.w += fmaxf(hd.w + hs0.w + et0.w, 0.f);
    }
    __shared__ float4 red[4][64];
    red[g][tl] = acc;
    __syncthreads();
    if (g == 0) {
        float4 a = red[0][tl], b = red[1][tl], c = red[2][tl], d = red[3][tl];
        float sv[4];
        sv[0] = (a.x + b.x) + (c.x + d.x);
        sv[1] = (a.y + b.y) + (c.y + d.y);
        sv[2] = (a.z + b.z) + (c.z + d.z);
        sv[3] = (a.w + b.w) + (c.w + d.w);
        f16x4 ph, pl;
#pragma unroll
        for (int j = 0; j < 4; j++) {
            float s = sv[j] * SCL;
            _Float16 h = (_Float16)s;
            ph[j] = h;
            pl[j] = (_Float16)(s - (float)h);
        }
        *(f16x4*)&Phi[(size_t)i * 256 + c4] = ph;
        *(f16x4*)&Plo[(size_t)i * 256 + c4] = pl;
    }
}

// ---------------- readout ----------------
__global__ void readout_scatter(const _Float16* __restrict__ hhi, const _Float16* __restrict__ hlo,
                                const int* __restrict__ vg, const int* __restrict__ vs,
                                float* __restrict__ sums, int* __restrict__ cnt) {
    int m = blockIdx.x * 2 + (threadIdx.x >> 7);
    int c = threadIdx.x & 127;
    if (m >= N_MENTIONS) return;
    int node = vg[m];
    int v = vs[m];
    size_t idx = (size_t)node * DMODEL + c;
    float x = ((float)hhi[idx] + (float)hlo[idx]) * SCLI;
    atomicAdd(&sums[(size_t)v * DMODEL + c], x);
    if (c == 0) atomicAdd(&cnt[v], 1);
}

__global__ void divide_kernel(float* __restrict__ sums, const int* __restrict__ cnt) {
    int v = blockIdx.x;
    int c = threadIdx.x;  // 128
    float d = (float)max(cnt[v], 1);
    sums[(size_t)v * DMODEL + c] /= d;
}

// ---------------- launcher ----------------
extern "C" void kernel_launch(void* const* d_in, const int* in_sizes, int n_in,
                              void* d_out, int out_size, void* d_ws, size_t ws_size,
                              hipStream_t stream) {
    const float* node_labels = (const float*)d_in[0];
    const int*   edges       = (const int*)d_in[1];
    const int*   edge_labels = (const int*)d_in[2];
    const int*   var_gather  = (const int*)d_in[3];
    const int*   var_scatter = (const int*)d_in[4];
    const float* enc_W0 = (const float*)d_in[7];
    const float* enc_b0 = (const float*)d_in[8];
    const float* enc_W1 = (const float*)d_in[9];
    const float* enc_b1 = (const float*)d_in[10];
    const float* edge_emb = (const float*)d_in[11];
    const float* mlp_W1 = (const float*)d_in[12];
    const float* mlp_b1 = (const float*)d_in[13];
    const float* mlp_W2 = (const float*)d_in[14];
    const float* mlp_b2 = (const float*)d_in[15];
    const float* dec_W0 = (const float*)d_in[16];
    const float* dec_b0 = (const float*)d_in[17];
    const float* dec_Wl = (const float*)d_in[18];
    const float* dec_bl = (const float*)d_in[19];
    float* out = (float*)d_out;

    char* ws = (char*)d_ws;
    size_t off = 0;
    auto alloc = [&](size_t bytes) -> void* {
        void* p = ws + off;
        off += (bytes + 255) & ~(size_t)255;
        return p;
    };
    float*    HH    = (float*)alloc((size_t)N_NODES * 512 * 4);       // 102.4 MB
    _Float16* hhi   = (_Float16*)alloc((size_t)N_NODES * DMODEL * 2); // 12.8 MB
    _Float16* hlo   = (_Float16*)alloc((size_t)N_NODES * DMODEL * 2);
    _Float16* Phi   = (_Float16*)alloc((size_t)N_NODES * 256 * 2);    // 25.6 MB
    _Float16* Plo   = (_Float16*)alloc((size_t)N_NODES * 256 * 2);
    float* etp  = (float*)alloc((size_t)N_ETYPES * 256 * 4);
    int* deg    = (int*)alloc((size_t)N_NODES * 4);
    int* offs   = (int*)alloc((size_t)(N_NODES + 1) * 4);
    int* cursor = (int*)alloc((size_t)N_NODES * 4);
    int* bsum   = (int*)alloc(64 * 4);
    int* src_s  = (int*)alloc((size_t)N_EDGES * 4);
    int* lab_s  = (int*)alloc((size_t)N_EDGES * 4);
    _Float16* W1t_h = (_Float16*)alloc((size_t)N_LAYERS * 512 * 128 * 2);
    _Float16* W1t_l = (_Float16*)alloc((size_t)N_LAYERS * 512 * 128 * 2);
    _Float16* W2t_h = (_Float16*)alloc((size_t)N_LAYERS * 128 * 256 * 2);
    _Float16* W2t_l = (_Float16*)alloc((size_t)N_LAYERS * 128 * 256 * 2);
    _Float16* e0h = (_Float16*)alloc(128 * 64 * 2);
    _Float16* e0l = (_Float16*)alloc(128 * 64 * 2);
    _Float16* e1h = (_Float16*)alloc(128 * 128 * 2);
    _Float16* e1l = (_Float16*)alloc(128 * 128 * 2);
    _Float16* d0h = (_Float16*)alloc(128 * 128 * 2);
    _Float16* d0l = (_Float16*)alloc(128 * 128 * 2);
    _Float16* dlh = (_Float16*)alloc(128 * 128 * 2);
    _Float16* dll = (_Float16*)alloc(128 * 128 * 2);
    _Float16* hench = (_Float16*)alloc((size_t)N_NODES * DMODEL * 2);
    _Float16* hencl = (_Float16*)alloc((size_t)N_NODES * DMODEL * 2);
    float* vsum = (float*)alloc((size_t)N_VARS * DMODEL * 4);
    int*   vcnt = (int*)alloc((size_t)N_VARS * 4);
    _Float16* dtmph = (_Float16*)alloc((size_t)N_VARS * DMODEL * 2);
    _Float16* dtmpl = (_Float16*)alloc((size_t)N_VARS * DMODEL * 2);

    const int* e_src = edges;
    const int* e_dst = edges + N_EDGES;

    hipMemsetAsync(deg, 0, (size_t)N_NODES * 4, stream);
    hipMemsetAsync(vsum, 0, (size_t)N_VARS * DMODEL * 4, stream);
    hipMemsetAsync(vcnt, 0, (size_t)N_VARS * 4, stream);

    // CSR build (hierarchical scan)
    count_deg<<<(N_EDGES + 255) / 256, 256, 0, stream>>>(e_dst, deg);
    scan_local<<<SCAN_NB, SCAN_B, 0, stream>>>(deg, offs, bsum, N_NODES);
    scan_block<<<1, 64, 0, stream>>>(bsum, SCAN_NB);
    scan_final<<<SCAN_NB, SCAN_B, 0, stream>>>(offs, bsum, cursor, N_NODES, N_EDGES);
    place_edges<<<(N_EDGES + 255) / 256, 256, 0, stream>>>(e_src, e_dst, edge_labels, cursor,
                                                           src_s, lab_s);

    // weight prep
    dim3 pb(16, 16);
    wprep<<<dim3(32, 8, N_LAYERS), pb, 0, stream>>>(mlp_W1, W1t_h, W1t_l, 128, 512, 512,
                                                    (long)384 * 256, (long)512 * 128, 1);
    wprep<<<dim3(8, 16, N_LAYERS), pb, 0, stream>>>(mlp_W2, W2t_h, W2t_l, 256, 128, 128,
                                                    (long)256 * 128, (long)128 * 256, 0);
    wprep<<<dim3(8, 4, 1), pb, 0, stream>>>(enc_W0, e0h, e0l, 64, 128, 128, 0, 0, 0);
    wprep<<<dim3(8, 8, 1), pb, 0, stream>>>(enc_W1, e1h, e1l, 128, 128, 128, 0, 0, 0);
    wprep<<<dim3(8, 8, 1), pb, 0, stream>>>(dec_W0, d0h, d0l, 128, 128, 128, 0, 0, 0);
    wprep<<<dim3(8, 8, 1), pb, 0, stream>>>(dec_Wl, dlh, dll, 128, 100, 128, 0, 0, 0);

    dim3 blk(256);
    const int MT_N = (N_NODES + 63) / 64;   // 782
    const int MT_V = (N_VARS + 63) / 64;    // 313

    // encoder: fp32-A in, split out; then split-A, split out
    gemm3h<EPI_BIAS_RELU, 0, 1><<<dim3(2, MT_N), blk, 0, stream>>>(
        node_labels, nullptr, nullptr, e0h, e0l, enc_b0, nullptr,
        nullptr, hench, hencl, N_NODES, 128, 64, 128);
    gemm3h<EPI_BIAS, 1, 1><<<dim3(2, MT_N), blk, 0, stream>>>(
        nullptr, hench, hencl, e1h, e1l, enc_b1, nullptr,
        nullptr, hhi, hlo, N_NODES, 128, 128, 128);

    // message-passing layers
    for (int l = 0; l < N_LAYERS; ++l) {
        const float* W1 = mlp_W1 + (size_t)l * 384 * 256;
        const float* b1 = mlp_b1 + (size_t)l * 256;
        const float* b2 = mlp_b2 + (size_t)l * DMODEL;
        const float* ee = edge_emb + (size_t)l * N_ETYPES * DMODEL;

        etype_proj_kernel<<<N_ETYPES, 256, 0, stream>>>(ee, W1 + 256 * 256, b1, etp);
        gemm3h<EPI_NONE, 1, 0><<<dim3(8, MT_N), blk, 0, stream>>>(
            nullptr, hhi, hlo, W1t_h + (size_t)l * 512 * 128, W1t_l + (size_t)l * 512 * 128,
            nullptr, nullptr, HH, nullptr, nullptr, N_NODES, 512, 128, 512);
        edge_agg<<<N_NODES, blk, 0, stream>>>(HH, etp, offs, src_s, lab_s, Phi, Plo);
        gemm3h<EPI_DEG_GELU, 1, 1><<<dim3(2, MT_N), blk, 0, stream>>>(
            nullptr, Phi, Plo, W2t_h + (size_t)l * 128 * 256, W2t_l + (size_t)l * 128 * 256,
            b2, deg, nullptr, hhi, hlo, N_NODES, 128, 256, 128);
    }

    // readout: scatter-mean into variables
    readout_scatter<<<(N_MENTIONS + 1) / 2, 256, 0, stream>>>(hhi, hlo, var_gather, var_scatter,
                                                              vsum, vcnt);
    divide_kernel<<<N_VARS, DMODEL, 0, stream>>>(vsum, vcnt);

    // decoder
    gemm3h<EPI_BIAS_RELU, 0, 1><<<dim3(2, MT_V), blk, 0, stream>>>(
        vsum, nullptr, nullptr, d0h, d0l, dec_b0, nullptr,
        nullptr, dtmph, dtmpl, N_VARS, 128, 128, 128);
    gemm3h<EPI_BIAS, 1, 0><<<dim3(2, MT_V), blk, 0, stream>>>(
        nullptr, dtmph, dtmpl, dlh, dll, dec_bl, nullptr,
        out, nullptr, nullptr, N_VARS, OUT_DIM, 128, OUT_DIM);
}

// Round 6
// 1701.473 us; speedup vs baseline: 2.1042x; 1.0407x over previous
//
#include <hip/hip_runtime.h>
#include <math.h>

#define N_NODES 50000
#define N_EDGES 600000
#define IN_DIM 64
#define DMODEL 128
#define N_LAYERS 8
#define N_ETYPES 44
#define N_MENTIONS 100000
#define N_VARS 20000
#define OUT_DIM 100

#define EPI_BIAS 0
#define EPI_BIAS_RELU 1
#define EPI_DEG_GELU 2
#define EPI_NONE 3

#define SCL  6.103515625e-05f   /* 2^-14: pre-scale into f16 range (|h| can reach ~1e7) */
#define SCLI 16384.0f

typedef _Float16 f16x8 __attribute__((ext_vector_type(8)));
typedef _Float16 f16x4 __attribute__((ext_vector_type(4)));
typedef float f32x4 __attribute__((ext_vector_type(4)));

__device__ __forceinline__ float gelu_exact(float x) {
    return 0.5f * x * (1.0f + erff(x * 0.70710678118654752f));
}

// ---------------- weight prep: transpose [K,N]->[Npad,K] and split fp32 -> f16 hi+lo ----------
__global__ void wprep(const float* __restrict__ src, _Float16* __restrict__ dhi,
                      _Float16* __restrict__ dlo, int K, int Nsrc, int Npad,
                      long srcLS, long dstLS, int cat) {
    __shared__ float sh[16][17];
    int z = blockIdx.z;
    src += (size_t)z * srcLS;
    dhi += (size_t)z * dstLS;
    dlo += (size_t)z * dstLS;
    int n0 = blockIdx.x * 16, k0 = blockIdx.y * 16;
    int tx = threadIdx.x, ty = threadIdx.y;
    int nr = n0 + tx, kr = k0 + ty;
    float v;
    if (cat) {
        int half = nr >> 8;
        int nc = nr & 255;
        v = src[(size_t)(kr + half * 128) * 256 + nc];
    } else {
        v = (nr < Nsrc) ? src[(size_t)kr * Nsrc + nr] : 0.f;
    }
    sh[ty][tx] = v;
    __syncthreads();
    float x = sh[tx][ty];
    int n = n0 + ty, k = k0 + tx;
    _Float16 hi = (_Float16)x;
    float lo = x - (float)hi;
    dhi[(size_t)n * K + k] = hi;
    dlo[(size_t)n * K + k] = (_Float16)lo;
}

// ---------------- 3xF16 MFMA GEMM ----------------
template<int EPI, int ASPLIT, int OSPLIT>
__global__ __launch_bounds__(256) void gemm3h(
        const float* __restrict__ A, const _Float16* __restrict__ Ahi,
        const _Float16* __restrict__ Alo,
        const _Float16* __restrict__ Bh, const _Float16* __restrict__ Bl,
        const float* __restrict__ bias, const int* __restrict__ deg,
        float* __restrict__ C, _Float16* __restrict__ Chi, _Float16* __restrict__ Clo,
        int M, int N, int K, int ldC) {
    __shared__ _Float16 Ah[64 * 56], Al[64 * 56], Bsh[64 * 56], Bsl[64 * 56];
    int t = threadIdx.x;
    int m0 = blockIdx.y * 64, n0 = blockIdx.x * 64;
    int ar = t >> 2, ac = (t & 3) * 8;
    int btt = t & 127, br = btt >> 1, bc = (btt & 1) * 16;
    const _Float16* Bsrc = (t < 128) ? Bh : Bl;
    _Float16* Bdst = (t < 128) ? Bsh : Bsl;
    int lane = t & 63, wid = t >> 6;
    int wm = (wid >> 1) * 32, wn = (wid & 1) * 32;
    int quad = lane >> 4, l15 = lane & 15;
    f32x4 acc[2][2] = {};
    bool arow_ok = (m0 + ar) < M;
    const float* Aptr = ASPLIT ? nullptr : (A + (size_t)(m0 + ar) * K + ac);
    const _Float16* Ahp = ASPLIT ? (Ahi + (size_t)(m0 + ar) * K + ac) : nullptr;
    const _Float16* Alp = ASPLIT ? (Alo + (size_t)(m0 + ar) * K + ac) : nullptr;
    const _Float16* Bptr = Bsrc + (size_t)(n0 + br) * K + bc;

    for (int k0 = 0; k0 < K; k0 += 32) {
        f16x8 hv = {}, lv = {};
        if (ASPLIT) {
            if (arow_ok) {
                hv = *(const f16x8*)(Ahp + k0);
                lv = *(const f16x8*)(Alp + k0);
            }
        } else {
            float4 v0 = {0, 0, 0, 0}, v1 = {0, 0, 0, 0};
            if (arow_ok) {
                v0 = *(const float4*)(Aptr + k0);
                v1 = *(const float4*)(Aptr + k0 + 4);
            }
            float xs[8] = {v0.x, v0.y, v0.z, v0.w, v1.x, v1.y, v1.z, v1.w};
#pragma unroll
            for (int j = 0; j < 8; j++) {
                float s = xs[j] * SCL;
                _Float16 h = (_Float16)s;
                hv[j] = h;
                lv[j] = (_Float16)(s - (float)h);
            }
        }
        *(f16x8*)&Ah[ar * 56 + ac] = hv;
        *(f16x8*)&Al[ar * 56 + ac] = lv;
        f16x8 b0 = *(const f16x8*)(Bptr + k0);
        f16x8 b1v = *(const f16x8*)(Bptr + k0 + 8);
        *(f16x8*)&Bdst[br * 56 + bc] = b0;
        *(f16x8*)&Bdst[br * 56 + bc + 8] = b1v;
        __syncthreads();

        f16x8 afh[2], afl[2], bfh[2], bfl[2];
#pragma unroll
        for (int i = 0; i < 2; i++) {
            int am = (wm + i * 16 + l15) * 56 + quad * 8;
            afh[i] = *(const f16x8*)&Ah[am];
            afl[i] = *(const f16x8*)&Al[am];
            int bn = (wn + i * 16 + l15) * 56 + quad * 8;
            bfh[i] = *(const f16x8*)&Bsh[bn];
            bfl[i] = *(const f16x8*)&Bsl[bn];
        }
#pragma unroll
        for (int i = 0; i < 2; i++)
#pragma unroll
            for (int j = 0; j < 2; j++) {
                acc[i][j] = __builtin_amdgcn_mfma_f32_16x16x32_f16(afh[i], bfh[j], acc[i][j], 0, 0, 0);
                acc[i][j] = __builtin_amdgcn_mfma_f32_16x16x32_f16(afh[i], bfl[j], acc[i][j], 0, 0, 0);
                acc[i][j] = __builtin_amdgcn_mfma_f32_16x16x32_f16(afl[i], bfh[j], acc[i][j], 0, 0, 0);
            }
        __syncthreads();
    }

#pragma unroll
    for (int i = 0; i < 2; i++) {
        int rowb = m0 + wm + i * 16 + quad * 4;
#pragma unroll
        for (int j = 0; j < 2; j++) {
            int col = n0 + wn + j * 16 + l15;
            if (col >= N) continue;
#pragma unroll
            for (int r = 0; r < 4; r++) {
                int row = rowb + r;
                if (row >= M) continue;
                float v = acc[i][j][r] * SCLI;
                if (EPI == EPI_BIAS) { v += bias[col]; }
                else if (EPI == EPI_BIAS_RELU) { v += bias[col]; v = fmaxf(v, 0.f); }
                else if (EPI == EPI_DEG_GELU) { v += (float)deg[row] * bias[col]; v = gelu_exact(v); }
                size_t idx = (size_t)row * ldC + col;
                if (OSPLIT) {
                    float s = v * SCL;
                    _Float16 h = (_Float16)s;
                    Chi[idx] = h;
                    Clo[idx] = (_Float16)(s - (float)h);
                } else {
                    C[idx] = v;
                }
            }
        }
    }
}

// ---------------- CSR build ----------------
__global__ void count_deg(const int* __restrict__ dst, int* __restrict__ deg) {
    int e = blockIdx.x * blockDim.x + threadIdx.x;
    if (e < N_EDGES) atomicAdd(&deg[dst[e]], 1);
}

#define SCAN_B 1024
#define SCAN_NB ((N_NODES + SCAN_B - 1) / SCAN_B)

__global__ void scan_local(const int* __restrict__ deg, int* __restrict__ offs,
                           int* __restrict__ bsum, int n) {
    __shared__ int sh[SCAN_B];
    int t = threadIdx.x;
    int i = blockIdx.x * SCAN_B + t;
    int v = (i < n) ? deg[i] : 0;
    sh[t] = v;
    __syncthreads();
    for (int o = 1; o < SCAN_B; o <<= 1) {
        int u = (t >= o) ? sh[t - o] : 0;
        __syncthreads();
        sh[t] += u;
        __syncthreads();
    }
    if (i < n) offs[i] = sh[t] - v;
    if (t == SCAN_B - 1) bsum[blockIdx.x] = sh[t];
}

__global__ void scan_block(int* __restrict__ bsum, int nb) {
    __shared__ int sh[64];
    int t = threadIdx.x;
    int v = (t < nb) ? bsum[t] : 0;
    sh[t] = v;
    __syncthreads();
    for (int o = 1; o < 64; o <<= 1) {
        int u = (t >= o) ? sh[t - o] : 0;
        __syncthreads();
        sh[t] += u;
        __syncthreads();
    }
    if (t < nb) bsum[t] = sh[t] - v;
}

__global__ void scan_final(int* __restrict__ offs, const int* __restrict__ bsum,
                           int* __restrict__ cursor, int n, int total) {
    int i = blockIdx.x * SCAN_B + threadIdx.x;
    if (i < n) {
        int o = offs[i] + bsum[blockIdx.x];
        offs[i] = o;
        cursor[i] = o;
    }
    if (i == n) offs[n] = total;
}

__global__ void place_edges(const int* __restrict__ src, const int* __restrict__ dst,
                            const int* __restrict__ lab, int* __restrict__ cursor,
                            int* __restrict__ src_s, int* __restrict__ lab_s) {
    int e = blockIdx.x * blockDim.x + threadIdx.x;
    if (e < N_EDGES) {
        int pos = atomicAdd(&cursor[dst[e]], 1);
        src_s[pos] = src[e];
        lab_s[pos] = lab[e];
    }
}

// ---------------- per-etype projection, all layers in one dispatch ----------------
__global__ void etype_proj_all(const float* __restrict__ edge_emb, const float* __restrict__ mlp_W1,
                               const float* __restrict__ mlp_b1, float* __restrict__ etp_all) {
    int et = blockIdx.x;   // 0..43
    int l  = blockIdx.y;   // 0..7
    int c = threadIdx.x;   // 256
    const float* ee = edge_emb + (size_t)l * N_ETYPES * DMODEL + (size_t)et * DMODEL;
    const float* W  = mlp_W1 + (size_t)l * 384 * 256 + (size_t)256 * 256;
    float s = mlp_b1[(size_t)l * 256 + c];
    for (int k = 0; k < DMODEL; k++)
        s += ee[k] * W[(size_t)k * 256 + c];
    etp_all[((size_t)l * N_ETYPES + et) * 256 + c] = s;
}

// ---------------- edge aggregation: wave-per-node, unroll x4 ----------------
// HH [N,512] fp32: cols 0..255 = Hd, 256..511 = Hs. Output pre-scaled f16 hi/lo pair.
__global__ __launch_bounds__(256) void edge_agg(
        const float* __restrict__ HH, const float* __restrict__ etp,
        const int* __restrict__ offsets, const int* __restrict__ src_s,
        const int* __restrict__ lab_s, _Float16* __restrict__ Phi,
        _Float16* __restrict__ Plo) {
    int wid = threadIdx.x >> 6, tl = threadIdx.x & 63;
    int i = blockIdx.x * 4 + wid;
    if (i >= N_NODES) return;
    int c4 = tl * 4;
    float4 hd = *(const float4*)&HH[(size_t)i * 512 + c4];
    float4 acc = {0.f, 0.f, 0.f, 0.f};
    int e0 = offsets[i], e1 = offsets[i + 1];
    int e = e0;
    for (; e + 3 < e1; e += 4) {
        int s0 = src_s[e],     l0 = lab_s[e];
        int s1 = src_s[e + 1], l1 = lab_s[e + 1];
        int s2 = src_s[e + 2], l2 = lab_s[e + 2];
        int s3 = src_s[e + 3], l3 = lab_s[e + 3];
        float4 hs0 = *(const float4*)&HH[(size_t)s0 * 512 + 256 + c4];
        float4 hs1 = *(const float4*)&HH[(size_t)s1 * 512 + 256 + c4];
        float4 hs2 = *(const float4*)&HH[(size_t)s2 * 512 + 256 + c4];
        float4 hs3 = *(const float4*)&HH[(size_t)s3 * 512 + 256 + c4];
        float4 et0 = *(const float4*)&etp[l0 * 256 + c4];
        float4 et1 = *(const float4*)&etp[l1 * 256 + c4];
        float4 et2 = *(const float4*)&etp[l2 * 256 + c4];
        float4 et3 = *(const float4*)&etp[l3 * 256 + c4];
        acc.x += fmaxf(hd.x + hs0.x + et0.x, 0.f) + fmaxf(hd.x + hs1.x + et1.x, 0.f)
               + fmaxf(hd.x + hs2.x + et2.x, 0.f) + fmaxf(hd.x + hs3.x + et3.x, 0.f);
        acc.y += fmaxf(hd.y + hs0.y + et0.y, 0.f) + fmaxf(hd.y + hs1.y + et1.y, 0.f)
               + fmaxf(hd.y + hs2.y + et2.y, 0.f) + fmaxf(hd.y + hs3.y + et3.y, 0.f);
        acc.z += fmaxf(hd.z + hs0.z + et0.z, 0.f) + fmaxf(hd.z + hs1.z + et1.z, 0.f)
               + fmaxf(hd.z + hs2.z + et2.z, 0.f) + fmaxf(hd.z + hs3.z + et3.z, 0.f);
        acc.w += fmaxf(hd.w + hs0.w + et0.w, 0.f) + fmaxf(hd.w + hs1.w + et1.w, 0.f)
               + fmaxf(hd.w + hs2.w + et2.w, 0.f) + fmaxf(hd.w + hs3.w + et3.w, 0.f);
    }
    for (; e < e1; ++e) {
        int s0 = src_s[e], l0 = lab_s[e];
        float4 hs0 = *(const float4*)&HH[(size_t)s0 * 512 + 256 + c4];
        float4 et0 = *(const float4*)&etp[l0 * 256 + c4];
        acc.x += fmaxf(hd.x + hs0.x + et0.x, 0.f);
        acc.y += fmaxf(hd.y + hs0.y + et0.y, 0.f);
        acc.z += fmaxf(hd.z + hs0.z + et0.z, 0.f);
        acc.w += fmaxf(hd.w + hs0.w + et0.w, 0.f);
    }
    float sv[4] = {acc.x, acc.y, acc.z, acc.w};
    f16x4 ph, pl;
#pragma unroll
    for (int j = 0; j < 4; j++) {
        float s = sv[j] * SCL;
        _Float16 h = (_Float16)s;
        ph[j] = h;
        pl[j] = (_Float16)(s - (float)h);
    }
    *(f16x4*)&Phi[(size_t)i * 256 + c4] = ph;
    *(f16x4*)&Plo[(size_t)i * 256 + c4] = pl;
}

// ---------------- readout ----------------
__global__ void readout_scatter(const _Float16* __restrict__ hhi, const _Float16* __restrict__ hlo,
                                const int* __restrict__ vg, const int* __restrict__ vs,
                                float* __restrict__ sums, int* __restrict__ cnt) {
    int m = blockIdx.x * 2 + (threadIdx.x >> 7);
    int c = threadIdx.x & 127;
    if (m >= N_MENTIONS) return;
    int node = vg[m];
    int v = vs[m];
    size_t idx = (size_t)node * DMODEL + c;
    float x = ((float)hhi[idx] + (float)hlo[idx]) * SCLI;
    atomicAdd(&sums[(size_t)v * DMODEL + c], x);
    if (c == 0) atomicAdd(&cnt[v], 1);
}

__global__ void divide_kernel(float* __restrict__ sums, const int* __restrict__ cnt) {
    int v = blockIdx.x;
    int c = threadIdx.x;  // 128
    float d = (float)max(cnt[v], 1);
    sums[(size_t)v * DMODEL + c] /= d;
}

// ---------------- launcher ----------------
extern "C" void kernel_launch(void* const* d_in, const int* in_sizes, int n_in,
                              void* d_out, int out_size, void* d_ws, size_t ws_size,
                              hipStream_t stream) {
    const float* node_labels = (const float*)d_in[0];
    const int*   edges       = (const int*)d_in[1];
    const int*   edge_labels = (const int*)d_in[2];
    const int*   var_gather  = (const int*)d_in[3];
    const int*   var_scatter = (const int*)d_in[4];
    const float* enc_W0 = (const float*)d_in[7];
    const float* enc_b0 = (const float*)d_in[8];
    const float* enc_W1 = (const float*)d_in[9];
    const float* enc_b1 = (const float*)d_in[10];
    const float* edge_emb = (const float*)d_in[11];
    const float* mlp_W1 = (const float*)d_in[12];
    const float* mlp_b1 = (const float*)d_in[13];
    const float* mlp_W2 = (const float*)d_in[14];
    const float* mlp_b2 = (const float*)d_in[15];
    const float* dec_W0 = (const float*)d_in[16];
    const float* dec_b0 = (const float*)d_in[17];
    const float* dec_Wl = (const float*)d_in[18];
    const float* dec_bl = (const float*)d_in[19];
    float* out = (float*)d_out;

    char* ws = (char*)d_ws;
    size_t off = 0;
    auto alloc = [&](size_t bytes) -> void* {
        void* p = ws + off;
        off += (bytes + 255) & ~(size_t)255;
        return p;
    };
    float*    HH    = (float*)alloc((size_t)N_NODES * 512 * 4);       // 102.4 MB
    _Float16* hhi   = (_Float16*)alloc((size_t)N_NODES * DMODEL * 2);
    _Float16* hlo   = (_Float16*)alloc((size_t)N_NODES * DMODEL * 2);
    _Float16* Phi   = (_Float16*)alloc((size_t)N_NODES * 256 * 2);
    _Float16* Plo   = (_Float16*)alloc((size_t)N_NODES * 256 * 2);
    float* etp_all = (float*)alloc((size_t)N_LAYERS * N_ETYPES * 256 * 4);
    int* deg    = (int*)alloc((size_t)N_NODES * 4);
    int* offs   = (int*)alloc((size_t)(N_NODES + 1) * 4);
    int* cursor = (int*)alloc((size_t)N_NODES * 4);
    int* bsum   = (int*)alloc(64 * 4);
    int* src_s  = (int*)alloc((size_t)N_EDGES * 4);
    int* lab_s  = (int*)alloc((size_t)N_EDGES * 4);
    _Float16* W1t_h = (_Float16*)alloc((size_t)N_LAYERS * 512 * 128 * 2);
    _Float16* W1t_l = (_Float16*)alloc((size_t)N_LAYERS * 512 * 128 * 2);
    _Float16* W2t_h = (_Float16*)alloc((size_t)N_LAYERS * 128 * 256 * 2);
    _Float16* W2t_l = (_Float16*)alloc((size_t)N_LAYERS * 128 * 256 * 2);
    _Float16* e0h = (_Float16*)alloc(128 * 64 * 2);
    _Float16* e0l = (_Float16*)alloc(128 * 64 * 2);
    _Float16* e1h = (_Float16*)alloc(128 * 128 * 2);
    _Float16* e1l = (_Float16*)alloc(128 * 128 * 2);
    _Float16* d0h = (_Float16*)alloc(128 * 128 * 2);
    _Float16* d0l = (_Float16*)alloc(128 * 128 * 2);
    _Float16* dlh = (_Float16*)alloc(128 * 128 * 2);
    _Float16* dll = (_Float16*)alloc(128 * 128 * 2);
    _Float16* hench = (_Float16*)alloc((size_t)N_NODES * DMODEL * 2);
    _Float16* hencl = (_Float16*)alloc((size_t)N_NODES * DMODEL * 2);
    float* vsum = (float*)alloc((size_t)N_VARS * DMODEL * 4);
    int*   vcnt = (int*)alloc((size_t)N_VARS * 4);
    _Float16* dtmph = (_Float16*)alloc((size_t)N_VARS * DMODEL * 2);
    _Float16* dtmpl = (_Float16*)alloc((size_t)N_VARS * DMODEL * 2);

    const int* e_src = edges;
    const int* e_dst = edges + N_EDGES;

    hipMemsetAsync(deg, 0, (size_t)N_NODES * 4, stream);
    hipMemsetAsync(vsum, 0, (size_t)N_VARS * DMODEL * 4, stream);
    hipMemsetAsync(vcnt, 0, (size_t)N_VARS * 4, stream);

    // CSR build (hierarchical scan)
    count_deg<<<(N_EDGES + 255) / 256, 256, 0, stream>>>(e_dst, deg);
    scan_local<<<SCAN_NB, SCAN_B, 0, stream>>>(deg, offs, bsum, N_NODES);
    scan_block<<<1, 64, 0, stream>>>(bsum, SCAN_NB);
    scan_final<<<SCAN_NB, SCAN_B, 0, stream>>>(offs, bsum, cursor, N_NODES, N_EDGES);
    place_edges<<<(N_EDGES + 255) / 256, 256, 0, stream>>>(e_src, e_dst, edge_labels, cursor,
                                                           src_s, lab_s);

    // weight prep
    dim3 pb(16, 16);
    wprep<<<dim3(32, 8, N_LAYERS), pb, 0, stream>>>(mlp_W1, W1t_h, W1t_l, 128, 512, 512,
                                                    (long)384 * 256, (long)512 * 128, 1);
    wprep<<<dim3(8, 16, N_LAYERS), pb, 0, stream>>>(mlp_W2, W2t_h, W2t_l, 256, 128, 128,
                                                    (long)256 * 128, (long)128 * 256, 0);
    wprep<<<dim3(8, 4, 1), pb, 0, stream>>>(enc_W0, e0h, e0l, 64, 128, 128, 0, 0, 0);
    wprep<<<dim3(8, 8, 1), pb, 0, stream>>>(enc_W1, e1h, e1l, 128, 128, 128, 0, 0, 0);
    wprep<<<dim3(8, 8, 1), pb, 0, stream>>>(dec_W0, d0h, d0l, 128, 128, 128, 0, 0, 0);
    wprep<<<dim3(8, 8, 1), pb, 0, stream>>>(dec_Wl, dlh, dll, 128, 100, 128, 0, 0, 0);

    // all-layer etype projections, one dispatch
    etype_proj_all<<<dim3(N_ETYPES, N_LAYERS), 256, 0, stream>>>(edge_emb, mlp_W1, mlp_b1, etp_all);

    dim3 blk(256);
    const int MT_N = (N_NODES + 63) / 64;   // 782
    const int MT_V = (N_VARS + 63) / 64;    // 313

    // encoder
    gemm3h<EPI_BIAS_RELU, 0, 1><<<dim3(2, MT_N), blk, 0, stream>>>(
        node_labels, nullptr, nullptr, e0h, e0l, enc_b0, nullptr,
        nullptr, hench, hencl, N_NODES, 128, 64, 128);
    gemm3h<EPI_BIAS, 1, 1><<<dim3(2, MT_N), blk, 0, stream>>>(
        nullptr, hench, hencl, e1h, e1l, enc_b1, nullptr,
        nullptr, hhi, hlo, N_NODES, 128, 128, 128);

    // message-passing layers
    for (int l = 0; l < N_LAYERS; ++l) {
        const float* b2 = mlp_b2 + (size_t)l * DMODEL;
        gemm3h<EPI_NONE, 1, 0><<<dim3(8, MT_N), blk, 0, stream>>>(
            nullptr, hhi, hlo, W1t_h + (size_t)l * 512 * 128, W1t_l + (size_t)l * 512 * 128,
            nullptr, nullptr, HH, nullptr, nullptr, N_NODES, 512, 128, 512);
        edge_agg<<<(N_NODES + 3) / 4, blk, 0, stream>>>(
            HH, etp_all + (size_t)l * N_ETYPES * 256, offs, src_s, lab_s, Phi, Plo);
        gemm3h<EPI_DEG_GELU, 1, 1><<<dim3(2, MT_N), blk, 0, stream>>>(
            nullptr, Phi, Plo, W2t_h + (size_t)l * 128 * 256, W2t_l + (size_t)l * 128 * 256,
            b2, deg, nullptr, hhi, hlo, N_NODES, 128, 256, 128);
    }

    // readout: scatter-mean into variables
    readout_scatter<<<(N_MENTIONS + 1) / 2, 256, 0, stream>>>(hhi, hlo, var_gather, var_scatter,
                                                              vsum, vcnt);
    divide_kernel<<<N_VARS, DMODEL, 0, stream>>>(vsum, vcnt);

    // decoder
    gemm3h<EPI_BIAS_RELU, 0, 1><<<dim3(2, MT_V), blk, 0, stream>>>(
        vsum, nullptr, nullptr, d0h, d0l, dec_b0, nullptr,
        nullptr, dtmph, dtmpl, N_VARS, 128, 128, 128);
    gemm3h<EPI_BIAS, 1, 0><<<dim3(2, MT_V), blk, 0, stream>>>(
        nullptr, dtmph, dtmpl, dlh, dll, dec_bl, nullptr,
        out, nullptr, nullptr, N_VARS, OUT_DIM, 128, OUT_DIM);
}